// Round 1
// baseline (1143.855 us; speedup 1.0000x reference)
//
#include <hip/hip_runtime.h>

#define B_      64
#define L_      8192
#define NB_     20
#define K_      769
#define GLEN    1537      // 2K-1 combined filter length
#define GPAD    1548      // multiple of 12, >= GLEN (zeros beyond GLEN)
#define GSTRIDE 1552      // g row stride in ws (16B aligned)
#define PADLEN  2307      // min(3K, L-1)
#define OFFSET  1539      // PADLEN - (K-1)
#define TILE    2048
#define STAGE_N 3600      // TILE + max window reach (1547+19 < 1552)

// ---------------------------------------------------------------------------
// Kernel 1: combined filter g[o,m] = sum_j k[o, K-1-j] * k[o, m-j]
// (autocorrelation of kernel o, length 2K-1; zero-padded to GPAD)
// grid (NB_, 8), block 256 — each y-block covers a 194-wide m chunk.
// ---------------------------------------------------------------------------
__global__ __launch_bounds__(256) void bp_combine(
    const float* __restrict__ kern, float* __restrict__ g)
{
    __shared__ __align__(16) float ks[K_];
    const int o   = blockIdx.x;
    const int tid = threadIdx.x;
    for (int i = tid; i < K_; i += 256) ks[i] = kern[o * K_ + i];
    __syncthreads();

    const int m = blockIdx.y * 194 + tid;
    if (tid < 194 && m < GPAD) {
        float acc = 0.f;
        if (m < GLEN) {
            const int jlo = (m > K_ - 1) ? (m - (K_ - 1)) : 0;
            const int jhi = (m < K_ - 1) ? m : (K_ - 1);
            for (int j = jlo; j <= jhi; ++j)
                acc = fmaf(ks[K_ - 1 - j], ks[m - j], acc);
        }
        g[o * GSTRIDE + m] = acc;
    }
}

// ---------------------------------------------------------------------------
// Kernel 2: z[b,o,t] = sum_m g[o,m] * xp[b, t + OFFSET + m]
// xp is the odd-reflect padded signal, materialized on the fly into LDS:
//   p in [0,PADLEN)            -> -x[b, PADLEN - p]
//   p in [PADLEN, PADLEN+L)    ->  x[b, p - PADLEN]
//   p in [PADLEN+L, Lp)        -> -x[b, (L-2) + (PADLEN+L) - p]
// One block per (b, o, 2048-tile). 256 threads x 8 consecutive outputs each.
// Sliding register window: 12 taps per macro-iteration.
// ---------------------------------------------------------------------------
__global__ __launch_bounds__(256) void bp_main(
    const float* __restrict__ x, const float* __restrict__ g,
    float* __restrict__ out)
{
    __shared__ __align__(16) float xs[STAGE_N];
    __shared__ __align__(16) float gs[GPAD];

    const int blk  = blockIdx.x;
    const int tile = blk & 3;                 // L_/TILE = 4
    const int o    = (blk >> 2) % NB_;
    const int b    = blk / (4 * NB_);
    const int tid  = threadIdx.x;

    const int T0 = tile * TILE;
    const float* __restrict__ xrow = x + b * L_;

    // stage combined filter
    for (int i = tid; i < GPAD; i += 256)
        gs[i] = g[o * GSTRIDE + i];

    // stage reflected x window: xp[p0 .. p0+STAGE_N)
    const int p0 = T0 + OFFSET;
    for (int i = tid; i < STAGE_N; i += 256) {
        const int p = p0 + i;
        float v;
        if (p < PADLEN)            v = -xrow[PADLEN - p];
        else if (p < PADLEN + L_)  v =  xrow[p - PADLEN];
        else                       v = -xrow[(L_ - 2) + (PADLEN + L_) - p];
        xs[i] = v;
    }
    __syncthreads();

    const int base = tid * 8;
    float acc[8] = {0.f, 0.f, 0.f, 0.f, 0.f, 0.f, 0.f, 0.f};

    float4 h0 = *(const float4*)&xs[base];
    float4 h1 = *(const float4*)&xs[base + 4];

    #pragma unroll 3
    for (int m = 0; m < GPAD; m += 12) {
        const float4 ga = *(const float4*)&gs[m];        // broadcast reads
        const float4 gb = *(const float4*)&gs[m + 4];
        const float4 gc = *(const float4*)&gs[m + 8];
        const float4 n0 = *(const float4*)&xs[base + m + 8];
        const float4 n1 = *(const float4*)&xs[base + m + 12];
        const float4 n2 = *(const float4*)&xs[base + m + 16];

        const float W[20] = {h0.x,h0.y,h0.z,h0.w, h1.x,h1.y,h1.z,h1.w,
                             n0.x,n0.y,n0.z,n0.w, n1.x,n1.y,n1.z,n1.w,
                             n2.x,n2.y,n2.z,n2.w};
        const float G[12] = {ga.x,ga.y,ga.z,ga.w, gb.x,gb.y,gb.z,gb.w,
                             gc.x,gc.y,gc.z,gc.w};

        #pragma unroll
        for (int s = 0; s < 12; ++s) {
            #pragma unroll
            for (int i = 0; i < 8; ++i)
                acc[i] = fmaf(G[s], W[s + i], acc[i]);
        }
        h0 = n1; h1 = n2;   // slide window by 12 (keep last 8)
    }

    // out shape (B, 1, NB, L): index = (b*NB + o)*L + t
    float4* op = (float4*)&out[(b * NB_ + o) * L_ + T0 + base];
    op[0] = make_float4(acc[0], acc[1], acc[2], acc[3]);
    op[1] = make_float4(acc[4], acc[5], acc[6], acc[7]);
}

extern "C" void kernel_launch(void* const* d_in, const int* in_sizes, int n_in,
                              void* d_out, int out_size, void* d_ws, size_t ws_size,
                              hipStream_t stream)
{
    const float* x    = (const float*)d_in[0];   // (B,1,L) f32
    const float* kern = (const float*)d_in[1];   // (NB,K) f32
    float*       out  = (float*)d_out;           // (B,1,NB,L) f32
    float*       g    = (float*)d_ws;            // NB * GSTRIDE floats (~124 KB)

    dim3 cgrid(NB_, 8);
    bp_combine<<<cgrid, 256, 0, stream>>>(kern, g);
    bp_main<<<B_ * NB_ * 4, 256, 0, stream>>>(x, g, out);
}

// Round 2
// 378.789 us; speedup vs baseline: 3.0198x; 3.0198x over previous
//
#include <hip/hip_runtime.h>

#define B_      64
#define L_      8192
#define NB_     20
#define K_      769
#define GLEN    1537      // 2K-1 combined filter length
#define GPAD    1548      // combine kernel zero-pads g rows to here
#define GSTRIDE 1552      // g row stride in ws (16B aligned)
#define GPAD2   1540      // taps processed by main kernel (mult of 4, >= GLEN)
#define PADLEN  2307      // min(3K, L-1)
#define OFFSET  1539      // PADLEN - (K-1)
#define TILE    4096
#define XS_N    5680      // TILE + GPAD2 + slack, swizzle-closed
#define GS_N    1552

// LDS word-index XOR swizzle (involution, preserves 16B blocks):
// spreads 64-byte-strided lane blocks across all 8 bank groups.
__device__ __forceinline__ int swz(int w) {
    int b = w >> 2;
    b ^= (b >> 3) & 3;
    return (b << 2) | (w & 3);
}

// ---------------------------------------------------------------------------
// Kernel 1: g[o,m] = sum_j k[o, K-1-j] * k[o, m-j]  (autocorrelation, 2K-1)
// ---------------------------------------------------------------------------
__global__ __launch_bounds__(256) void bp_combine(
    const float* __restrict__ kern, float* __restrict__ g)
{
    __shared__ __align__(16) float ks[K_];
    const int o   = blockIdx.x;
    const int tid = threadIdx.x;
    for (int i = tid; i < K_; i += 256) ks[i] = kern[o * K_ + i];
    __syncthreads();

    const int m = blockIdx.y * 194 + tid;
    if (tid < 194 && m < GPAD) {
        float acc = 0.f;
        if (m < GLEN) {
            const int jlo = (m > K_ - 1) ? (m - (K_ - 1)) : 0;
            const int jhi = (m < K_ - 1) ? m : (K_ - 1);
            for (int j = jlo; j <= jhi; ++j)
                acc = fmaf(ks[K_ - 1 - j], ks[m - j], acc);
        }
        g[o * GSTRIDE + m] = acc;
    }
}

// ---------------------------------------------------------------------------
// Kernel 2: z[b,o,t] = sum_m g[o,m] * xp[b, t + OFFSET + m]
// One block per (b, o, 4096-tile). 256 threads x 16 consecutive outputs.
// Rotating 5-slot float4 register window, 4 taps per group, g prefetched.
// ---------------------------------------------------------------------------
__global__ __launch_bounds__(256) void bp_main(
    const float* __restrict__ x, const float* __restrict__ g,
    float* __restrict__ out)
{
    __shared__ __align__(16) float xs[XS_N];
    __shared__ __align__(16) float gs[GS_N];

    const int blk  = blockIdx.x;
    const int tile = blk & 1;                 // L_/TILE = 2
    const int o    = (blk >> 1) % NB_;
    const int b    = blk / (2 * NB_);
    const int tid  = threadIdx.x;

    const int T0 = tile * TILE;
    const float* __restrict__ xrow = x + b * L_;

    // stage combined filter (broadcast-read later; no swizzle)
    for (int i = tid; i < GS_N; i += 256)
        gs[i] = (i < GPAD) ? g[o * GSTRIDE + i] : 0.f;

    // stage reflected x window xp[p0 .. p0+XS_N) with swizzled writes
    const int p0 = T0 + OFFSET;
    for (int i = tid; i < XS_N; i += 256) {
        const int p = p0 + i;
        float v;
        if (p < PADLEN)            v = -xrow[PADLEN - p];
        else if (p < PADLEN + L_)  v =  xrow[p - PADLEN];
        else                       v = -xrow[(L_ - 2) + (PADLEN + L_) - p];
        xs[swz(i)] = v;
    }
    __syncthreads();

    const int base = tid * 16;
    float acc[16];
    #pragma unroll
    for (int i = 0; i < 16; ++i) acc[i] = 0.f;

    // rotating register window: w[0..4] hold xs[base+mm .. base+mm+19]
    float4 w[5];
    #pragma unroll
    for (int j = 0; j < 5; ++j)
        w[j] = *(const float4*)&xs[swz(base + 4 * j)];

    float4 gv = *(const float4*)&gs[0];   // taps 0..3 (uniform addr: broadcast)

    int mm = 0;
    for (int it = 0; it < GPAD2 / 20; ++it) {     // 77 iterations
        #pragma unroll
        for (int p = 0; p < 5; ++p) {
            // prefetch next x block (window element 20) and next g taps
            const float4 nw = *(const float4*)&xs[swz(base + mm + 20)];
            const float4 gn = *(const float4*)&gs[mm + 4];

            // window element e (0..18) lives in w[(p + e/4) % 5][e % 4]
            const float W[20] = {
                w[(p + 0) % 5].x, w[(p + 0) % 5].y, w[(p + 0) % 5].z, w[(p + 0) % 5].w,
                w[(p + 1) % 5].x, w[(p + 1) % 5].y, w[(p + 1) % 5].z, w[(p + 1) % 5].w,
                w[(p + 2) % 5].x, w[(p + 2) % 5].y, w[(p + 2) % 5].z, w[(p + 2) % 5].w,
                w[(p + 3) % 5].x, w[(p + 3) % 5].y, w[(p + 3) % 5].z, w[(p + 3) % 5].w,
                w[(p + 4) % 5].x, w[(p + 4) % 5].y, w[(p + 4) % 5].z, w[(p + 4) % 5].w };
            const float G[4] = { gv.x, gv.y, gv.z, gv.w };

            #pragma unroll
            for (int s = 0; s < 4; ++s) {
                #pragma unroll
                for (int i = 0; i < 16; ++i)
                    acc[i] = fmaf(G[s], W[s + i], acc[i]);
            }

            w[p % 5] = nw;   // slot p held elements 0..3, retired after this group
            gv = gn;
            mm += 4;
        }
    }

    // out shape (B, 1, NB, L): index = (b*NB + o)*L + t
    float4* op = (float4*)&out[(b * NB_ + o) * L_ + T0 + base];
    #pragma unroll
    for (int q = 0; q < 4; ++q)
        op[q] = make_float4(acc[4*q], acc[4*q+1], acc[4*q+2], acc[4*q+3]);
}

extern "C" void kernel_launch(void* const* d_in, const int* in_sizes, int n_in,
                              void* d_out, int out_size, void* d_ws, size_t ws_size,
                              hipStream_t stream)
{
    const float* x    = (const float*)d_in[0];   // (B,1,L) f32
    const float* kern = (const float*)d_in[1];   // (NB,K) f32
    float*       out  = (float*)d_out;           // (B,1,NB,L) f32
    float*       g    = (float*)d_ws;            // NB * GSTRIDE floats (~124 KB)

    dim3 cgrid(NB_, 8);
    bp_combine<<<cgrid, 256, 0, stream>>>(kern, g);
    bp_main<<<B_ * NB_ * 2, 256, 0, stream>>>(x, g, out);
}

// Round 3
// 341.331 us; speedup vs baseline: 3.3512x; 1.1097x over previous
//
#include <hip/hip_runtime.h>

#define B_      64
#define L_      8192
#define NB_     20
#define K_      769
#define GLEN    1537      // 2K-1 combined filter length
#define GPAD3   1560      // taps processed by main kernel (39 * 40), zero-padded
#define GSTRIDE 1568      // g row stride in ws (16B aligned, >= GPAD3 + 8 tail slack)
#define PADLEN  2307      // min(3K, L-1)
#define OFFSET  1539      // PADLEN - (K-1)
#define XS_N    9760      // words staged: 8191 + 1554 + slack, swizzle-closed
#define NOUT    32        // outputs per thread

// Block-index swizzle (involution): bits0-2 ^= bits3-5. With 32-word lane
// stride, block = 8*lane + d, so lane bits land in the bank-group bits ->
// conflict-free ds_read_b128 for any uniform window offset d.
__device__ __forceinline__ int swzblk(int b) { return b ^ ((b >> 3) & 7); }

__device__ __forceinline__ float fsel(const float4& v, int c) {
    return c == 0 ? v.x : c == 1 ? v.y : c == 2 ? v.z : v.w;
}

// ---------------------------------------------------------------------------
// Kernel 1: g[o,m] = sum_j k[o, K-1-j] * k[o, m-j]  (autocorrelation, 2K-1)
// zero-padded through GPAD3. grid (NB_, 8) x 256; 195-wide m chunks.
// ---------------------------------------------------------------------------
__global__ __launch_bounds__(256) void bp_combine(
    const float* __restrict__ kern, float* __restrict__ g)
{
    __shared__ __align__(16) float ks[K_];
    const int o   = blockIdx.x;
    const int tid = threadIdx.x;
    for (int i = tid; i < K_; i += 256) ks[i] = kern[o * K_ + i];
    __syncthreads();

    const int m = blockIdx.y * 195 + tid;
    if (tid < 195 && m < GPAD3) {
        float acc = 0.f;
        if (m < GLEN) {
            const int jlo = (m > K_ - 1) ? (m - (K_ - 1)) : 0;
            const int jhi = (m < K_ - 1) ? m : (K_ - 1);
            for (int j = jlo; j <= jhi; ++j)
                acc = fmaf(ks[K_ - 1 - j], ks[m - j], acc);
        }
        g[o * GSTRIDE + m] = acc;
    }
}

// ---------------------------------------------------------------------------
// Kernel 2: z[b,o,t] = sum_m g[o,m] * xp[b, t + OFFSET + m]
// One block per (b,o), full 8192-wide row. 256 threads x 32 outputs.
// x window in swizzled LDS; g read uniform (scalar/broadcast) from global.
// 10-slot rotating float4 window, 10 groups (40 taps) per macro-iteration.
// ---------------------------------------------------------------------------
__global__ __launch_bounds__(256, 4) void bp_main(
    const float* __restrict__ x, const float* __restrict__ g,
    float* __restrict__ out)
{
    __shared__ __align__(16) float xs[XS_N];

    const int o   = blockIdx.x % NB_;
    const int b   = blockIdx.x / NB_;
    const int tid = threadIdx.x;

    const float* __restrict__ xrow = x + b * L_;
    const float* __restrict__ grow = g + o * GSTRIDE;   // block-uniform row

    // stage reflected x window xp[OFFSET .. OFFSET+XS_N) with swizzled writes
    for (int i = tid; i < XS_N; i += 256) {
        const int p = OFFSET + i;
        float v;
        if (p < PADLEN)            v = -xrow[PADLEN - p];
        else if (p < PADLEN + L_)  v =  xrow[p - PADLEN];
        else                       v = -xrow[(L_ - 2) + (PADLEN + L_) - p];
        xs[(swzblk(i >> 2) << 2) | (i & 3)] = v;
    }
    __syncthreads();

    const int B0 = (tid * NOUT) >> 2;     // thread's base block (= 8*tid)

    float acc[NOUT];
    #pragma unroll
    for (int i = 0; i < NOUT; ++i) acc[i] = 0.f;

    // rotating window: slot (p + j) % 10 holds block B0 + 10*it + p + j
    float4 w[10];
    #pragma unroll
    for (int j = 0; j < 9; ++j)
        w[j] = *(const float4*)&xs[swzblk(B0 + j) << 2];

    // g rotator: gq[p%5] holds taps for group p; prefetched 2 groups ahead
    float4 gq[5];
    gq[0] = *(const float4*)&grow[0];
    gq[1] = *(const float4*)&grow[4];

    for (int it = 0; it < GPAD3 / 40; ++it) {        // 39 iterations
        const int mm = it * 40;
        #pragma unroll
        for (int p = 0; p < 10; ++p) {
            // prefetch x block for the next group's window tail
            w[(p + 9) % 10] = *(const float4*)&xs[swzblk(B0 + 10 * it + p + 9) << 2];
            // prefetch g taps for group p+2 (uniform address -> scalar load)
            if (p < 8) gq[(p + 2) % 5] = *(const float4*)&grow[mm + 4 * (p + 2)];
            else       gq[(p + 2) % 5] = *(const float4*)&grow[mm + 40 + 4 * (p - 8)];

            const float4 gv = gq[p % 5];
            #pragma unroll
            for (int s = 0; s < 4; ++s) {
                const float gt = fsel(gv, s);
                #pragma unroll
                for (int oo = 0; oo < NOUT; ++oo) {
                    const int e = s + oo;                       // 0..34
                    const float xv = fsel(w[(p + (e >> 2)) % 10], e & 3);
                    acc[oo] = fmaf(gt, xv, acc[oo]);
                }
            }
        }
    }

    // out shape (B, 1, NB, L): index = (b*NB + o)*L + t
    float4* op = (float4*)&out[(b * NB_ + o) * L_ + tid * NOUT];
    #pragma unroll
    for (int q = 0; q < 8; ++q)
        op[q] = make_float4(acc[4*q], acc[4*q+1], acc[4*q+2], acc[4*q+3]);
}

extern "C" void kernel_launch(void* const* d_in, const int* in_sizes, int n_in,
                              void* d_out, int out_size, void* d_ws, size_t ws_size,
                              hipStream_t stream)
{
    const float* x    = (const float*)d_in[0];   // (B,1,L) f32
    const float* kern = (const float*)d_in[1];   // (NB,K) f32
    float*       out  = (float*)d_out;           // (B,1,NB,L) f32
    float*       g    = (float*)d_ws;            // NB * GSTRIDE floats (~125 KB)

    dim3 cgrid(NB_, 8);
    bp_combine<<<cgrid, 256, 0, stream>>>(kern, g);
    bp_main<<<B_ * NB_, 256, 0, stream>>>(x, g, out);
}

// Round 4
// 93.683 us; speedup vs baseline: 12.2098x; 3.6435x over previous
//
#include <hip/hip_runtime.h>

#define B_      64
#define L_      8192
#define NB_     20
#define K_      769
#define GLEN    1537        // 2K-1 combined filter length
#define GSTRIDE 1552        // f32 g row stride (words)
#define PADLEN  2307        // min(3K, L-1)
#define OFFSET  1539        // PADLEN - (K-1)
#define NSTEP   97          // K-steps of 16 taps: 97*16 = 1552 >= GLEN
#define TB      512         // t-tile per block
#define NW      2184        // staged window halves
#define CP_H    2176        // valid halves per parity copy
#define CPS_H   2184        // copy stride in halves (1092 words: +4-word bank skew)

typedef _Float16 half8  __attribute__((ext_vector_type(8)));
typedef float    f32x16 __attribute__((ext_vector_type(16)));

// ---------------------------------------------------------------------------
// Kernel 1: g[o,m] = sum_j k[o, K-1-j] * k[o, m-j]  (autocorrelation, f32)
// ---------------------------------------------------------------------------
__global__ __launch_bounds__(256) void bp_combine(
    const float* __restrict__ kern, float* __restrict__ g)
{
    __shared__ __align__(16) float ks[K_];
    const int o   = blockIdx.x;
    const int tid = threadIdx.x;
    for (int i = tid; i < K_; i += 256) ks[i] = kern[o * K_ + i];
    __syncthreads();

    const int m = blockIdx.y * 194 + tid;
    if (tid < 194 && m < GSTRIDE) {
        float acc = 0.f;
        if (m < GLEN) {
            const int jlo = (m > K_ - 1) ? (m - (K_ - 1)) : 0;
            const int jhi = (m < K_ - 1) ? m : (K_ - 1);
            for (int j = jlo; j <= jhi; ++j)
                acc = fmaf(ks[K_ - 1 - j], ks[m - j], acc);
        }
        g[o * GSTRIDE + m] = acc;
    }
}

// ---------------------------------------------------------------------------
// Kernel 2: pack g (scaled x1024) into MFMA A-fragment layout, f16.
// Fragment t = step*64 + lane: elem e = g1024[o = l&31, 16*step + 8*(l>>5) + e]
// One zero step appended (NSTEP+1 total) so main loop can prefetch blindly.
// ---------------------------------------------------------------------------
__global__ __launch_bounds__(256) void bp_pack(
    const float* __restrict__ g, _Float16* __restrict__ gbuf)
{
    const int t = blockIdx.x * 256 + threadIdx.x;
    if (t >= (NSTEP + 1) * 64) return;
    const int step = t >> 6;
    const int l    = t & 63;
    const int o    = l & 31;
    const int h5   = l >> 5;
    half8 f;
    #pragma unroll
    for (int e = 0; e < 8; ++e) {
        const int tap = 16 * step + 8 * h5 + e;
        float v = 0.f;
        if (step < NSTEP && o < NB_ && tap < GLEN)
            v = g[o * GSTRIDE + tap] * 1024.0f;
        f[e] = (_Float16)v;
    }
    *((half8*)gbuf + t) = f;
}

// ---------------------------------------------------------------------------
// Kernel 3: C[o, t-tile] = sum_k gfrag[o,k] * xp-Toeplitz[k, t]  via
// v_mfma_f32_32x32x16_f16. One block per (b, 512-wide tile); 4 waves x
// 4 subtiles of 32 t each. x window staged as 8 parity-shifted f16 copies
// so each B-fragment is ONE 16B-aligned conflict-balanced ds_read_b128.
// ---------------------------------------------------------------------------
__global__ __launch_bounds__(256, 4) void bp_mfma(
    const float* __restrict__ x, const _Float16* __restrict__ gbuf,
    float* __restrict__ out)
{
    __shared__ __align__(16) _Float16 xcp[8 * CPS_H];

    const int blk  = blockIdx.x;
    const int tile = blk & 15;              // L/TB = 16
    const int b    = blk >> 4;
    const int tid  = threadIdx.x;
    const int l    = tid & 63;
    const int w    = tid >> 6;

    const int T0 = tile * TB;
    const float* __restrict__ xrow = x + b * L_;

    // stage reflected window as f16, 8 parity-shifted copies
    for (int i = tid; i < NW; i += 256) {
        const int p = T0 + OFFSET + i;
        float v;
        if (p < PADLEN)            v = -xrow[PADLEN - p];
        else if (p < PADLEN + L_)  v =  xrow[p - PADLEN];
        else                       v = -xrow[(L_ - 2) + (PADLEN + L_) - p];
        const _Float16 h = (_Float16)v;
        #pragma unroll
        for (int c = 0; c < 8; ++c) {
            const int j = i - c;
            if (j >= 0 && j < CP_H) xcp[c * CPS_H + j] = h;
        }
    }
    __syncthreads();

    const int c  = l & 7;
    const int u  = l & 31;
    const int h5 = l >> 5;

    f32x16 acc[4];
    #pragma unroll
    for (int q = 0; q < 4; ++q)
        #pragma unroll
        for (int r = 0; r < 16; ++r) acc[q][r] = 0.f;

    // byte offset of subtile-0 fragment at step 0 (16B-aligned by parity copy)
    const char* lb0 = (const char*)xcp
                    + c * (CPS_H * 2)
                    + 2 * (128 * w + u + 8 * h5 - c);

    const half8* gfp = (const half8*)gbuf + l;     // + 64 per step
    half8 gf = gfp[0];

    for (int step = 0; step < NSTEP; ++step) {
        const half8 gnx = gfp[(step + 1) * 64];    // zero pad step -> safe
        const char* lb  = lb0 + 32 * step;
        #pragma unroll
        for (int q = 0; q < 4; ++q) {
            const half8 xf = *(const half8*)(lb + 64 * q);
            acc[q] = __builtin_amdgcn_mfma_f32_32x32x16_f16(gf, xf, acc[q], 0, 0, 0);
        }
        gf = gnx;
    }

    // D layout (m101): col = l&31 (=t-local), row = (r&3)+8*(r>>2)+4*(l>>5) (=o)
    const float sc = 1.0f / 1024.0f;
    #pragma unroll
    for (int q = 0; q < 4; ++q) {
        const int tb = T0 + 32 * (4 * w + q) + u;
        #pragma unroll
        for (int r = 0; r < 16; ++r) {
            const int o = (r & 3) + 8 * (r >> 2) + 4 * h5;
            if (o < NB_)
                out[((b * NB_ + o) << 13) + tb] = acc[q][r] * sc;
        }
    }
}

extern "C" void kernel_launch(void* const* d_in, const int* in_sizes, int n_in,
                              void* d_out, int out_size, void* d_ws, size_t ws_size,
                              hipStream_t stream)
{
    const float* x    = (const float*)d_in[0];   // (B,1,L) f32
    const float* kern = (const float*)d_in[1];   // (NB,K) f32
    float*       out  = (float*)d_out;           // (B,1,NB,L) f32

    float*     g    = (float*)d_ws;                          // 124 KB
    _Float16*  gbuf = (_Float16*)((char*)d_ws + 131072);     // 98*64*16B = 100 KB

    bp_combine<<<dim3(NB_, 8), 256, 0, stream>>>(kern, g);
    bp_pack<<<25, 256, 0, stream>>>(g, gbuf);
    bp_mfma<<<B_ * (L_ / TB), 256, 0, stream>>>(x, gbuf, out);
}

// Round 5
// 65.023 us; speedup vs baseline: 17.5916x; 1.4408x over previous
//
#include <hip/hip_runtime.h>

#define B_      64
#define L_      8192
#define NB_     20
#define K_      769
#define GLEN    1537        // 2K-1 combined filter length
#define GSM     1552        // g row length (f32), = 97*16
#define NSTEP   97
#define NSTEPP  104         // padded steps = 13 chunks * 8
#define CHUNK   8
#define NCHUNK  13
#define TB      512         // t-tile per block
#define CPS_H   2072        // copy stride (halves): 16B-aligned, quad-skew 3 (coprime 8)
#define NW      2072        // staged halves per copy
#define PADLEN  2307        // min(3K, L-1)
#define OFFSET  1539        // PADLEN - (K-1)
#define PBUF    (NB_ * GSM) // partial-g buffer stride (floats)

typedef _Float16 half8  __attribute__((ext_vector_type(8)));
typedef float    f32x16 __attribute__((ext_vector_type(16)));

// ---------------------------------------------------------------------------
// Kernel 1: partial autocorrelation. grid (NB, 8, 4): j-range split 4-way.
// gpart[jc][o][m] = sum_{j in chunk jc} k[o,K-1-j] * k[o,m-j]
// ---------------------------------------------------------------------------
__global__ __launch_bounds__(256) void bp_combine(
    const float* __restrict__ kern, float* __restrict__ gpart)
{
    __shared__ __align__(16) float ks[K_];
    const int o   = blockIdx.x;
    const int jc  = blockIdx.z;
    const int tid = threadIdx.x;
    for (int i = tid; i < K_; i += 256) ks[i] = kern[o * K_ + i];
    __syncthreads();

    const int m = blockIdx.y * 194 + tid;
    if (tid < 194 && m < GSM) {
        float acc = 0.f;
        int jlo = (m > K_ - 1) ? (m - (K_ - 1)) : 0;
        int jhi = (m < K_ - 1) ? m : (K_ - 1);
        if (jlo < jc * 193) jlo = jc * 193;
        if (jhi > jc * 193 + 192) jhi = jc * 193 + 192;
        for (int j = jlo; j <= jhi; ++j)
            acc = fmaf(ks[K_ - 1 - j], ks[m - j], acc);
        gpart[jc * PBUF + o * GSM + m] = acc;
    }
}

// ---------------------------------------------------------------------------
// Kernel 2: sum partials, scale x1024, pack into MFMA A-fragment layout (f16).
// Fragment t = step*64 + l: elem e = g1024[o = l&31, 16*step + 8*(l>>5) + e]
// ---------------------------------------------------------------------------
__global__ __launch_bounds__(256) void bp_pack(
    const float* __restrict__ gpart, _Float16* __restrict__ gbuf)
{
    const int t = blockIdx.x * 256 + threadIdx.x;
    if (t >= NSTEPP * 64) return;
    const int step = t >> 6;
    const int l    = t & 63;
    const int o    = l & 31;
    const int h5   = l >> 5;
    half8 f;
    #pragma unroll
    for (int e = 0; e < 8; ++e) {
        const int tap = 16 * step + 8 * h5 + e;
        float v = 0.f;
        if (o < NB_ && tap < GLEN) {
            const int idx = o * GSM + tap;
            v = (gpart[idx] + gpart[PBUF + idx] +
                 gpart[2 * PBUF + idx] + gpart[3 * PBUF + idx]) * 1024.0f;
        }
        f[e] = (_Float16)v;
    }
    *((half8*)gbuf + t) = f;
}

// ---------------------------------------------------------------------------
// Kernel 3: C[o, t] = sum_k g[o,k] * Toeplitz(xp)[k, t] via mfma 32x32x16 f16.
// One block per (b, 512-tile); 4 waves x 4 subtiles. x fragments come from
// 8 parity-shifted LDS copies through rotating register chains E[4]/O[4]
// (1 ds_read_b128 per step). g staged per-8-step-chunk into LDS via
// global_load_lds, whole chunk pulled to gq[8] registers at chunk start.
// ---------------------------------------------------------------------------
#define STAGE_G(chunki)                                                        \
    do {                                                                       \
        const int s0_ = (chunki) * CHUNK + 2 * w;                              \
        __builtin_amdgcn_global_load_lds(                                      \
            (const __attribute__((address_space(1))) void*)(gsrc + (size_t)s0_ * 1024 + l * 16), \
            (__attribute__((address_space(3))) void*)&gls[(2 * w) * 512], 16, 0, 0); \
        __builtin_amdgcn_global_load_lds(                                      \
            (const __attribute__((address_space(1))) void*)(gsrc + (size_t)(s0_ + 1) * 1024 + l * 16), \
            (__attribute__((address_space(3))) void*)&gls[(2 * w + 1) * 512], 16, 0, 0); \
    } while (0)

__global__ __launch_bounds__(256, 3) void bp_mfma(
    const float* __restrict__ x, const _Float16* __restrict__ gbuf,
    float* __restrict__ out)
{
    __shared__ __align__(16) _Float16 xcp[8 * CPS_H + 16];   // +pad: discarded tail read
    __shared__ __align__(16) _Float16 gls[CHUNK * 512];      // 8 KB, single buffer

    const int blk  = blockIdx.x;
    const int tile = blk & 15;              // L/TB = 16
    const int b    = blk >> 4;
    const int tid  = threadIdx.x;
    const int l    = tid & 63;
    const int w    = tid >> 6;

    const int T0 = tile * TB;
    const float* __restrict__ xrow = x + b * L_;
    const char*  __restrict__ gsrc = (const char*)gbuf;

    // stage reflected window as f16, 8 parity-shifted copies
    for (int i = tid; i < NW; i += 256) {
        const int p = T0 + OFFSET + i;
        float v;
        if (p < PADLEN)            v = -xrow[PADLEN - p];
        else if (p < PADLEN + L_)  v =  xrow[p - PADLEN];
        else                       v = -xrow[(L_ - 2) + (PADLEN + L_) - p];
        const _Float16 h = (_Float16)v;
        #pragma unroll
        for (int c = 0; c < 8; ++c) {
            const int j = i - c;
            if (j >= 0) xcp[c * CPS_H + j] = h;
        }
    }
    STAGE_G(0);
    __syncthreads();

    const int c  = l & 7;
    const int u  = l & 31;
    const int h5 = l >> 5;

    f32x16 acc[4];
    #pragma unroll
    for (int q = 0; q < 4; ++q)
        #pragma unroll
        for (int r = 0; r < 16; ++r) acc[q][r] = 0.f;

    // fragment base: 16B-aligned thanks to parity copy c = l&7
    const char* lb0 = (const char*)xcp + c * (CPS_H * 2)
                    + 2 * (128 * w + u + 8 * h5 - c);

    half8 E[4], O[4];
    #pragma unroll
    for (int j = 0; j < 4; ++j) {
        E[j] = *(const half8*)(lb0 + 64 * j);
        O[j] = *(const half8*)(lb0 + 32 + 64 * j);
    }

    const _Float16* gl = gls + l * 8;      // lane base inside a 1KB step slab
    const char* lb = lb0;

    for (int m = 0; m < 12; ++m) {
        // pull whole current chunk (8 steps) of g into registers
        half8 gq[8];
        #pragma unroll
        for (int s = 0; s < 8; ++s)
            gq[s] = *(const half8*)(gl + s * 512);
        __syncthreads();                       // all waves done reading gls
        if (m < 12) STAGE_G(m + 1);            // overwrite with next chunk

        #pragma unroll
        for (int uu = 0; uu < 8; ++uu) {
            if ((uu & 1) == 0) {
                const int r = uu >> 1;
                acc[0] = __builtin_amdgcn_mfma_f32_32x32x16_f16(gq[uu], E[(r + 0) & 3], acc[0], 0, 0, 0);
                acc[1] = __builtin_amdgcn_mfma_f32_32x32x16_f16(gq[uu], E[(r + 1) & 3], acc[1], 0, 0, 0);
                acc[2] = __builtin_amdgcn_mfma_f32_32x32x16_f16(gq[uu], E[(r + 2) & 3], acc[2], 0, 0, 0);
                acc[3] = __builtin_amdgcn_mfma_f32_32x32x16_f16(gq[uu], E[(r + 3) & 3], acc[3], 0, 0, 0);
                E[r & 3] = *(const half8*)(lb + 64 * (r + 4));
            } else {
                const int r = uu >> 1;
                acc[0] = __builtin_amdgcn_mfma_f32_32x32x16_f16(gq[uu], O[(r + 0) & 3], acc[0], 0, 0, 0);
                acc[1] = __builtin_amdgcn_mfma_f32_32x32x16_f16(gq[uu], O[(r + 1) & 3], acc[1], 0, 0, 0);
                acc[2] = __builtin_amdgcn_mfma_f32_32x32x16_f16(gq[uu], O[(r + 2) & 3], acc[2], 0, 0, 0);
                acc[3] = __builtin_amdgcn_mfma_f32_32x32x16_f16(gq[uu], O[(r + 3) & 3], acc[3], 0, 0, 0);
                O[r & 3] = *(const half8*)(lb + 32 + 64 * (r + 4));
            }
        }
        lb += 256;
        __syncthreads();                       // aligns waves + drains stage
    }

    // tail: step 96 (chunk 12, slot 0); E[q] holds fragment j = 48+q
    {
        const half8 g96 = *(const half8*)(gl + 0 * 512);
        acc[0] = __builtin_amdgcn_mfma_f32_32x32x16_f16(g96, E[0], acc[0], 0, 0, 0);
        acc[1] = __builtin_amdgcn_mfma_f32_32x32x16_f16(g96, E[1], acc[1], 0, 0, 0);
        acc[2] = __builtin_amdgcn_mfma_f32_32x32x16_f16(g96, E[2], acc[2], 0, 0, 0);
        acc[3] = __builtin_amdgcn_mfma_f32_32x32x16_f16(g96, E[3], acc[3], 0, 0, 0);
    }

    // D layout: col = l&31 (t-local), row = (r&3)+8*(r>>2)+4*(l>>5) (o)
    const float sc = 1.0f / 1024.0f;
    #pragma unroll
    for (int q = 0; q < 4; ++q) {
        const int tb = T0 + 32 * (4 * w + q) + u;
        #pragma unroll
        for (int r = 0; r < 16; ++r) {
            const int o = (r & 3) + 8 * (r >> 2) + 4 * h5;
            if (o < NB_)
                out[((b * NB_ + o) << 13) + tb] = acc[q][r] * sc;
        }
    }
}

extern "C" void kernel_launch(void* const* d_in, const int* in_sizes, int n_in,
                              void* d_out, int out_size, void* d_ws, size_t ws_size,
                              hipStream_t stream)
{
    const float* x    = (const float*)d_in[0];   // (B,1,L) f32
    const float* kern = (const float*)d_in[1];   // (NB,K) f32
    float*       out  = (float*)d_out;           // (B,1,NB,L) f32

    float*    gpart = (float*)d_ws;                           // 4*20*1552*4 = 496640 B
    _Float16* gbuf  = (_Float16*)((char*)d_ws + 496640);      // 104*1024 = 106496 B

    bp_combine<<<dim3(NB_, 8, 4), 256, 0, stream>>>(kern, gpart);
    bp_pack<<<26, 256, 0, stream>>>(gpart, gbuf);
    bp_mfma<<<B_ * (L_ / TB), 256, 0, stream>>>(x, gbuf, out);
}